// Round 1
// 713.561 us; speedup vs baseline: 1.0291x; 1.0291x over previous
//
#include <hip/hip_runtime.h>

#define DMODEL 128

// ================= CSR build =================
__global__ void cnt_kernel(const int* __restrict__ dst, int* __restrict__ cnt, int E) {
    int e = blockIdx.x * blockDim.x + threadIdx.x;
    if (e < E) atomicAdd(&cnt[dst[e]], 1);
}

// inclusive scan within 256-blocks + block totals
__global__ void scan1_kernel(const int* __restrict__ cnt, int* __restrict__ incl,
                             int* __restrict__ bsum, int n) {
    __shared__ int s[256];
    int t = threadIdx.x;
    int i = blockIdx.x * 256 + t;
    int v = (i < n) ? cnt[i] : 0;
    s[t] = v;
    __syncthreads();
    for (int off = 1; off < 256; off <<= 1) {
        int add = (t >= off) ? s[t - off] : 0;
        __syncthreads();
        s[t] += add;
        __syncthreads();
    }
    if (i < n) incl[i] = s[t];
    if (t == 255) bsum[blockIdx.x] = s[255];
}

// single-block exclusive scan of block sums (in place)
__global__ void scan2_kernel(int* __restrict__ bsum, int nb) {
    __shared__ int s[256];
    __shared__ int carry;
    int t = threadIdx.x;
    if (t == 0) carry = 0;
    __syncthreads();
    for (int base = 0; base < nb; base += 256) {
        int idx = base + t;
        int v = (idx < nb) ? bsum[idx] : 0;
        s[t] = v;
        __syncthreads();
        for (int off = 1; off < 256; off <<= 1) {
            int add = (t >= off) ? s[t - off] : 0;
            __syncthreads();
            s[t] += add;
            __syncthreads();
        }
        int excl = carry + s[t] - v;
        if (idx < nb) bsum[idx] = excl;
        __syncthreads();
        if (t == 255) carry += s[255];
    }
}

// offsets/cursor/dinv from scan pieces
__global__ void scan3_kernel(const int* __restrict__ cnt, const int* __restrict__ incl,
                             const int* __restrict__ bsum, int* __restrict__ offsets,
                             int* __restrict__ cursor, float* __restrict__ dinv,
                             int n, int E) {
    int i = blockIdx.x * 256 + threadIdx.x;
    if (i < n) {
        int v = cnt[i];
        int excl = incl[i] - v + bsum[blockIdx.x];
        offsets[i] = excl;
        cursor[i] = excl;
        dinv[i] = rsqrtf((float)v + 1.0f);
    }
    if (i == 0) offsets[n] = E;
}

// counting-sort fill of packed edge records {src, w = dinv[src]*dinv[dst]}
__global__ void fill_kernel(const int* __restrict__ src, const int* __restrict__ dst,
                            int* __restrict__ cursor, const float* __restrict__ dinv,
                            int2* __restrict__ er, int E) {
    int e = blockIdx.x * blockDim.x + threadIdx.x;
    if (e < E) {
        int s = src[e];
        int d = dst[e];
        int p = atomicAdd(&cursor[d], 1);
        er[p] = make_int2(s, __float_as_int(dinv[s] * dinv[d]));
    }
}

// ================= GEMM: C[n,128] = A[n,128] * W[128,128] =================
// 128x128 block tile (full output width), BK=32 K-split staging.
// LDS = sA[32][132] + sW[32][128] = 32.5 KB -> 4 blocks/CU (vs old 64 KB -> 2).
// 8x8 register blocking: per k, 4x ds_read_b128 feed 64 FMAs (LDS-BW balanced).
// Fragments split as {x, 64+x} so all b128 LDS reads are <=2-way bank aliased.
__global__ __launch_bounds__(256, 4) void gemm_kernel(const float* __restrict__ A,
                                                      const float* __restrict__ W,
                                                      float* __restrict__ C, int n) {
    __shared__ float sA[32][132];   // [k][r], +4 pad keeps 16B alignment, breaks k-stride aliasing
    __shared__ float sW[32][128];   // [k][c]
    const int tid  = threadIdx.x;
    const int row0 = blockIdx.x * 128;
    const int tx = tid & 15;        // col groups: tx*4 and 64+tx*4
    const int ty = tid >> 4;        // row groups: ty*4 and 64+ty*4

    float acc[8][8];
#pragma unroll
    for (int i = 0; i < 8; ++i)
#pragma unroll
        for (int j = 0; j < 8; ++j) acc[i][j] = 0.f;

    for (int kt = 0; kt < 128; kt += 32) {
        // ---- stage A transposed: sA[k][r] <- A[row0+r][kt+k] ----
        // wave reads 8 rows x 128B contiguous chunks (coalesced)
#pragma unroll
        for (int p = 0; p < 4; ++p) {
            int r  = p * 32 + (tid >> 3);
            int kq = tid & 7;
            int row = row0 + r;
            float4 v = make_float4(0.f, 0.f, 0.f, 0.f);
            if (row < n) v = *(const float4*)&A[(size_t)row * DMODEL + kt + kq * 4];
            sA[kq * 4 + 0][r] = v.x;
            sA[kq * 4 + 1][r] = v.y;
            sA[kq * 4 + 2][r] = v.z;
            sA[kq * 4 + 3][r] = v.w;
        }
        // ---- stage W direct: sW[k][c] <- W[kt+k][c] (fully coalesced float4) ----
#pragma unroll
        for (int q = 0; q < 4; ++q) {
            int f  = q * 256 + tid;
            int k  = f >> 5;
            int c4 = f & 31;
            *(float4*)&sW[k][c4 * 4] = *(const float4*)&W[(size_t)(kt + k) * DMODEL + c4 * 4];
        }
        __syncthreads();

#pragma unroll 8
        for (int k = 0; k < 32; ++k) {
            float4 a0 = *(const float4*)&sA[k][ty * 4];
            float4 a1 = *(const float4*)&sA[k][64 + ty * 4];
            float4 w0 = *(const float4*)&sW[k][tx * 4];
            float4 w1 = *(const float4*)&sW[k][64 + tx * 4];
            float av[8] = {a0.x, a0.y, a0.z, a0.w, a1.x, a1.y, a1.z, a1.w};
            float wv[8] = {w0.x, w0.y, w0.z, w0.w, w1.x, w1.y, w1.z, w1.w};
#pragma unroll
            for (int i = 0; i < 8; ++i)
#pragma unroll
                for (int j = 0; j < 8; ++j)
                    acc[i][j] += av[i] * wv[j];
        }
        __syncthreads();
    }

#pragma unroll
    for (int i = 0; i < 8; ++i) {
        int r = row0 + (i < 4 ? ty * 4 + i : 64 + ty * 4 + (i - 4));
        if (r < n) {
            *(float4*)&C[(size_t)r * DMODEL + tx * 4] =
                make_float4(acc[i][0], acc[i][1], acc[i][2], acc[i][3]);
            *(float4*)&C[(size_t)r * DMODEL + 64 + tx * 4] =
                make_float4(acc[i][4], acc[i][5], acc[i][6], acc[i][7]);
        }
    }
}

// ================= pull aggregation (fused self-loop + bias + relu) =================
// one 64-lane wave per node; lane owns 2 channels; 4-way unrolled edge loop
// (4 independent 512B row-gathers in flight per wave).
__global__ __launch_bounds__(256) void pull_kernel(const float* __restrict__ hw,
                                                   const int* __restrict__ offsets,
                                                   const int2* __restrict__ er,
                                                   const float* __restrict__ dinv,
                                                   const float* __restrict__ bias,
                                                   float* __restrict__ out1,
                                                   float* __restrict__ out2,
                                                   int n, int relu) {
    int node = blockIdx.x * 4 + (threadIdx.x >> 6);
    int lane = threadIdx.x & 63;
    if (node >= n) return;
    const float2* hwv = (const float2*)hw;
    float di = dinv[node];
    float s2 = di * di;
    float2 selfv = hwv[(size_t)node * 64 + lane];
    float2 a0, a1, a2, a3;
    a0.x = selfv.x * s2 + bias[lane * 2];
    a0.y = selfv.y * s2 + bias[lane * 2 + 1];
    a1 = make_float2(0.f, 0.f);
    a2 = make_float2(0.f, 0.f);
    a3 = make_float2(0.f, 0.f);
    int e0 = offsets[node];
    int e1 = offsets[node + 1];
    int e = e0;
    for (; e + 4 <= e1; e += 4) {
        int2 r0 = er[e];
        int2 r1 = er[e + 1];
        int2 r2 = er[e + 2];
        int2 r3 = er[e + 3];
        float2 v0 = hwv[(size_t)r0.x * 64 + lane];
        float2 v1 = hwv[(size_t)r1.x * 64 + lane];
        float2 v2 = hwv[(size_t)r2.x * 64 + lane];
        float2 v3 = hwv[(size_t)r3.x * 64 + lane];
        float w0 = __int_as_float(r0.y);
        float w1 = __int_as_float(r1.y);
        float w2 = __int_as_float(r2.y);
        float w3 = __int_as_float(r3.y);
        a0.x += v0.x * w0; a0.y += v0.y * w0;
        a1.x += v1.x * w1; a1.y += v1.y * w1;
        a2.x += v2.x * w2; a2.y += v2.y * w2;
        a3.x += v3.x * w3; a3.y += v3.y * w3;
    }
    for (; e < e1; ++e) {
        int2 r = er[e];
        float w = __int_as_float(r.y);
        float2 v = hwv[(size_t)r.x * 64 + lane];
        a0.x += v.x * w;
        a0.y += v.y * w;
    }
    float2 acc;
    acc.x = (a0.x + a1.x) + (a2.x + a3.x);
    acc.y = (a0.y + a1.y) + (a2.y + a3.y);
    if (relu) {
        acc.x = fmaxf(acc.x, 0.f);
        acc.y = fmaxf(acc.y, 0.f);
    }
    ((float2*)out1)[(size_t)node * 64 + lane] = acc;
    if (out2) ((float2*)out2)[(size_t)node * 64 + lane] = acc;
}

// duplicate result into both output halves (fallback path only)
__global__ void dup_kernel(const float4* __restrict__ s, float4* __restrict__ a,
                           float4* __restrict__ b, int n4) {
    int i = blockIdx.x * blockDim.x + threadIdx.x;
    if (i < n4) {
        float4 v = s[i];
        a[i] = v;
        b[i] = v;
    }
}

extern "C" void kernel_launch(void* const* d_in, const int* in_sizes, int n_in,
                              void* d_out, int out_size, void* d_ws, size_t ws_size,
                              hipStream_t stream) {
    const float* x  = (const float*)d_in[0];
    const int*   ei = (const int*)d_in[1];
    const float* W1 = (const float*)d_in[2];
    const float* b1 = (const float*)d_in[3];
    const float* W2 = (const float*)d_in[4];
    const float* b2 = (const float*)d_in[5];
    float* out = (float*)d_out;

    const int n = in_sizes[0] / DMODEL;     // 169343
    const int E = in_sizes[1] / 2;          // 1166243
    const int* src = ei;
    const int* dst = ei + E;

    const long long nd = (long long)n * DMODEL;
    const int NB = (n + 255) / 256;
    const int Na = NB * 256;
    const int NBa = ((NB + 255) / 256) * 256;
    const int Ea = ((E + 255) / 256) * 256;

    float* outA = out;
    float* outB = out + nd;

    // ---- d_ws base: dinv + hw ping buffer ----
    float* dinv  = (float*)d_ws;
    float* hwbuf = dinv + Na;

    // CSR arrays: primary = in d_ws (after hwbuf); fallback = in outA region.
    const size_t need_ints = (size_t)Na + (size_t)nd + 4ull * Na + NBa + 256 + 2ull * Ea;
    const bool ws_csr = ws_size >= need_ints * sizeof(int);

    int* base = ws_csr ? (int*)(hwbuf + nd) : (int*)outA;
    int* cnt     = base;                    // Na
    int* incl    = cnt + Na;                // Na
    int* bsum    = incl + Na;               // NBa
    int* offsets = bsum + NBa;              // Na + 256
    int* cursor  = offsets + Na + 256;      // Na
    int2* er     = (int2*)(cursor + Na);    // E records

    // ---- build CSR (sorted-by-dst packed edge records) ----
    hipMemsetAsync(cnt, 0, (size_t)n * sizeof(int), stream);
    cnt_kernel<<<(E + 255) / 256, 256, 0, stream>>>(dst, cnt, E);
    scan1_kernel<<<NB, 256, 0, stream>>>(cnt, incl, bsum, n);
    scan2_kernel<<<1, 256, 0, stream>>>(bsum, NB);
    scan3_kernel<<<NB, 256, 0, stream>>>(cnt, incl, bsum, offsets, cursor, dinv, n, E);
    fill_kernel<<<(E + 255) / 256, 256, 0, stream>>>(src, dst, cursor, dinv, er, E);

    dim3 ggrid((n + 127) / 128);
    const int pull_grid = (n + 3) / 4;

    if (ws_csr) {
        // layer 1: hw1 = x@W1 -> hwbuf; h = relu(agg) -> outB
        gemm_kernel<<<ggrid, 256, 0, stream>>>(x, W1, hwbuf, n);
        pull_kernel<<<pull_grid, 256, 0, stream>>>(hwbuf, offsets, er, dinv, b1,
                                                   outB, nullptr, n, 1);
        // layer 2: hw2 = h@W2 -> hwbuf; out = agg -> both halves directly
        gemm_kernel<<<ggrid, 256, 0, stream>>>(outB, W2, hwbuf, n);
        pull_kernel<<<pull_grid, 256, 0, stream>>>(hwbuf, offsets, er, dinv, b2,
                                                   outA, outB, n, 0);
    } else {
        // fallback (CSR scratch occupies outA until the end)
        gemm_kernel<<<ggrid, 256, 0, stream>>>(x, W1, outB, n);
        pull_kernel<<<pull_grid, 256, 0, stream>>>(outB, offsets, er, dinv, b1,
                                                   hwbuf, nullptr, n, 1);
        gemm_kernel<<<ggrid, 256, 0, stream>>>(hwbuf, W2, outB, n);
        pull_kernel<<<pull_grid, 256, 0, stream>>>(outB, offsets, er, dinv, b2,
                                                   hwbuf, nullptr, n, 0);
        const int n4 = (int)(nd / 4);
        dup_kernel<<<(n4 + 255) / 256, 256, 0, stream>>>((const float4*)hwbuf,
                                                         (float4*)outA, (float4*)outB, n4);
    }
}

// Round 2
// 629.325 us; speedup vs baseline: 1.1669x; 1.1339x over previous
//
#include <hip/hip_runtime.h>
#include <hip/hip_fp16.h>

#define DMODEL 128

// ================= CSR build =================
__global__ void cnt_kernel(const int* __restrict__ dst, int* __restrict__ cnt, int E) {
    int e = blockIdx.x * blockDim.x + threadIdx.x;
    if (e < E) atomicAdd(&cnt[dst[e]], 1);
}

// inclusive scan within 256-blocks + block totals
__global__ void scan1_kernel(const int* __restrict__ cnt, int* __restrict__ incl,
                             int* __restrict__ bsum, int n) {
    __shared__ int s[256];
    int t = threadIdx.x;
    int i = blockIdx.x * 256 + t;
    int v = (i < n) ? cnt[i] : 0;
    s[t] = v;
    __syncthreads();
    for (int off = 1; off < 256; off <<= 1) {
        int add = (t >= off) ? s[t - off] : 0;
        __syncthreads();
        s[t] += add;
        __syncthreads();
    }
    if (i < n) incl[i] = s[t];
    if (t == 255) bsum[blockIdx.x] = s[255];
}

// single-block exclusive scan of block sums (in place)
__global__ void scan2_kernel(int* __restrict__ bsum, int nb) {
    __shared__ int s[256];
    __shared__ int carry;
    int t = threadIdx.x;
    if (t == 0) carry = 0;
    __syncthreads();
    for (int base = 0; base < nb; base += 256) {
        int idx = base + t;
        int v = (idx < nb) ? bsum[idx] : 0;
        s[t] = v;
        __syncthreads();
        for (int off = 1; off < 256; off <<= 1) {
            int add = (t >= off) ? s[t - off] : 0;
            __syncthreads();
            s[t] += add;
            __syncthreads();
        }
        int excl = carry + s[t] - v;
        if (idx < nb) bsum[idx] = excl;
        __syncthreads();
        if (t == 255) carry += s[255];
    }
}

// offsets/cursor/dinv from scan pieces
__global__ void scan3_kernel(const int* __restrict__ cnt, const int* __restrict__ incl,
                             const int* __restrict__ bsum, int* __restrict__ offsets,
                             int* __restrict__ cursor, float* __restrict__ dinv,
                             int n, int E) {
    int i = blockIdx.x * 256 + threadIdx.x;
    if (i < n) {
        int v = cnt[i];
        int excl = incl[i] - v + bsum[blockIdx.x];
        offsets[i] = excl;
        cursor[i] = excl;
        dinv[i] = rsqrtf((float)v + 1.0f);
    }
    if (i == 0) offsets[n] = E;
}

// counting-sort fill of packed edge records {src, w = dinv[src]*dinv[dst]}
__global__ void fill_kernel(const int* __restrict__ src, const int* __restrict__ dst,
                            int* __restrict__ cursor, const float* __restrict__ dinv,
                            int2* __restrict__ er, int E) {
    int e = blockIdx.x * blockDim.x + threadIdx.x;
    if (e < E) {
        int s = src[e];
        int d = dst[e];
        int p = atomicAdd(&cursor[d], 1);
        er[p] = make_int2(s, __float_as_int(dinv[s] * dinv[d]));
    }
}

// ================= GEMM: C[n,128] = A[n,128] * W[128,128] =================
// 128x128 block tile, BK=32 K-split staging (32.5 KB LDS -> 4 blocks/CU).
// 8x8 register blocking; fragments split {x, 64+x} -> <=2-way LDS bank aliasing.
// OUT_HALF: write C as fp16 (gather operand for pull) to halve gather working set.
template <int OUT_HALF>
__global__ __launch_bounds__(256, 4) void gemm_kernel(const float* __restrict__ A,
                                                      const float* __restrict__ W,
                                                      void* __restrict__ Cout, int n) {
    __shared__ float sA[32][132];   // [k][r], +4 pad keeps 16B alignment
    __shared__ float sW[32][128];   // [k][c]
    const int tid  = threadIdx.x;
    const int row0 = blockIdx.x * 128;
    const int tx = tid & 15;
    const int ty = tid >> 4;

    float acc[8][8];
#pragma unroll
    for (int i = 0; i < 8; ++i)
#pragma unroll
        for (int j = 0; j < 8; ++j) acc[i][j] = 0.f;

    for (int kt = 0; kt < 128; kt += 32) {
#pragma unroll
        for (int p = 0; p < 4; ++p) {
            int r  = p * 32 + (tid >> 3);
            int kq = tid & 7;
            int row = row0 + r;
            float4 v = make_float4(0.f, 0.f, 0.f, 0.f);
            if (row < n) v = *(const float4*)&A[(size_t)row * DMODEL + kt + kq * 4];
            sA[kq * 4 + 0][r] = v.x;
            sA[kq * 4 + 1][r] = v.y;
            sA[kq * 4 + 2][r] = v.z;
            sA[kq * 4 + 3][r] = v.w;
        }
#pragma unroll
        for (int q = 0; q < 4; ++q) {
            int f  = q * 256 + tid;
            int k  = f >> 5;
            int c4 = f & 31;
            *(float4*)&sW[k][c4 * 4] = *(const float4*)&W[(size_t)(kt + k) * DMODEL + c4 * 4];
        }
        __syncthreads();

#pragma unroll 8
        for (int k = 0; k < 32; ++k) {
            float4 a0 = *(const float4*)&sA[k][ty * 4];
            float4 a1 = *(const float4*)&sA[k][64 + ty * 4];
            float4 w0 = *(const float4*)&sW[k][tx * 4];
            float4 w1 = *(const float4*)&sW[k][64 + tx * 4];
            float av[8] = {a0.x, a0.y, a0.z, a0.w, a1.x, a1.y, a1.z, a1.w};
            float wv[8] = {w0.x, w0.y, w0.z, w0.w, w1.x, w1.y, w1.z, w1.w};
#pragma unroll
            for (int i = 0; i < 8; ++i)
#pragma unroll
                for (int j = 0; j < 8; ++j)
                    acc[i][j] += av[i] * wv[j];
        }
        __syncthreads();
    }

#pragma unroll
    for (int i = 0; i < 8; ++i) {
        int r = row0 + (i < 4 ? ty * 4 + i : 64 + ty * 4 + (i - 4));
        if (r < n) {
            if (OUT_HALF) {
                __half* Ch = (__half*)Cout;
                union { __half2 h2[2]; uint2 u; } p0, p1;
                p0.h2[0] = __floats2half2_rn(acc[i][0], acc[i][1]);
                p0.h2[1] = __floats2half2_rn(acc[i][2], acc[i][3]);
                p1.h2[0] = __floats2half2_rn(acc[i][4], acc[i][5]);
                p1.h2[1] = __floats2half2_rn(acc[i][6], acc[i][7]);
                *(uint2*)&Ch[(size_t)r * DMODEL + tx * 4] = p0.u;
                *(uint2*)&Ch[(size_t)r * DMODEL + 64 + tx * 4] = p1.u;
            } else {
                float* Cf = (float*)Cout;
                *(float4*)&Cf[(size_t)r * DMODEL + tx * 4] =
                    make_float4(acc[i][0], acc[i][1], acc[i][2], acc[i][3]);
                *(float4*)&Cf[(size_t)r * DMODEL + 64 + tx * 4] =
                    make_float4(acc[i][4], acc[i][5], acc[i][6], acc[i][7]);
            }
        }
    }
}

// ================= pull aggregation (fused self-loop + bias + relu) =================
// one 64-lane wave per node; lane owns 2 channels (one half2 = 4B gather/lane);
// 4-way unrolled edge loop (4 independent 256B row-gathers in flight per wave).
// hw is fp16 (halved gather working set); all accumulation in f32.
__global__ __launch_bounds__(256) void pull_kernel(const __half* __restrict__ hw,
                                                   const int* __restrict__ offsets,
                                                   const int2* __restrict__ er,
                                                   const float* __restrict__ dinv,
                                                   const float* __restrict__ bias,
                                                   float* __restrict__ out1,
                                                   float* __restrict__ out2,
                                                   int n, int relu) {
    int node = blockIdx.x * 4 + (threadIdx.x >> 6);
    int lane = threadIdx.x & 63;
    if (node >= n) return;
    const __half2* hwv = (const __half2*)hw;
    float di = dinv[node];
    float s2 = di * di;
    float2 selfv = __half22float2(hwv[(size_t)node * 64 + lane]);
    float2 a0, a1, a2, a3;
    a0.x = selfv.x * s2 + bias[lane * 2];
    a0.y = selfv.y * s2 + bias[lane * 2 + 1];
    a1 = make_float2(0.f, 0.f);
    a2 = make_float2(0.f, 0.f);
    a3 = make_float2(0.f, 0.f);
    int e0 = offsets[node];
    int e1 = offsets[node + 1];
    int e = e0;
    for (; e + 4 <= e1; e += 4) {
        int2 r0 = er[e];
        int2 r1 = er[e + 1];
        int2 r2 = er[e + 2];
        int2 r3 = er[e + 3];
        __half2 h0 = hwv[(size_t)r0.x * 64 + lane];
        __half2 h1 = hwv[(size_t)r1.x * 64 + lane];
        __half2 h2 = hwv[(size_t)r2.x * 64 + lane];
        __half2 h3 = hwv[(size_t)r3.x * 64 + lane];
        float2 v0 = __half22float2(h0);
        float2 v1 = __half22float2(h1);
        float2 v2 = __half22float2(h2);
        float2 v3 = __half22float2(h3);
        float w0 = __int_as_float(r0.y);
        float w1 = __int_as_float(r1.y);
        float w2 = __int_as_float(r2.y);
        float w3 = __int_as_float(r3.y);
        a0.x += v0.x * w0; a0.y += v0.y * w0;
        a1.x += v1.x * w1; a1.y += v1.y * w1;
        a2.x += v2.x * w2; a2.y += v2.y * w2;
        a3.x += v3.x * w3; a3.y += v3.y * w3;
    }
    for (; e < e1; ++e) {
        int2 r = er[e];
        float w = __int_as_float(r.y);
        float2 v = __half22float2(hwv[(size_t)r.x * 64 + lane]);
        a0.x += v.x * w;
        a0.y += v.y * w;
    }
    float2 acc;
    acc.x = (a0.x + a1.x) + (a2.x + a3.x);
    acc.y = (a0.y + a1.y) + (a2.y + a3.y);
    if (relu) {
        acc.x = fmaxf(acc.x, 0.f);
        acc.y = fmaxf(acc.y, 0.f);
    }
    ((float2*)out1)[(size_t)node * 64 + lane] = acc;
    if (out2) ((float2*)out2)[(size_t)node * 64 + lane] = acc;
}

// duplicate result into both output halves (fallback path only)
__global__ void dup_kernel(const float4* __restrict__ s, float4* __restrict__ a,
                           float4* __restrict__ b, int n4) {
    int i = blockIdx.x * blockDim.x + threadIdx.x;
    if (i < n4) {
        float4 v = s[i];
        a[i] = v;
        b[i] = v;
    }
}

extern "C" void kernel_launch(void* const* d_in, const int* in_sizes, int n_in,
                              void* d_out, int out_size, void* d_ws, size_t ws_size,
                              hipStream_t stream) {
    const float* x  = (const float*)d_in[0];
    const int*   ei = (const int*)d_in[1];
    const float* W1 = (const float*)d_in[2];
    const float* b1 = (const float*)d_in[3];
    const float* W2 = (const float*)d_in[4];
    const float* b2 = (const float*)d_in[5];
    float* out = (float*)d_out;

    const int n = in_sizes[0] / DMODEL;     // 169343
    const int E = in_sizes[1] / 2;          // 1166243
    const int* src = ei;
    const int* dst = ei + E;

    const long long nd = (long long)n * DMODEL;
    const int NB = (n + 255) / 256;
    const int Na = NB * 256;
    const int NBa = ((NB + 255) / 256) * 256;
    const int Ea = ((E + 255) / 256) * 256;

    float* outA = out;
    float* outB = out + nd;

    // ---- d_ws base: dinv + hw ping buffer (fp16 now, region kept float-sized) ----
    float* dinv  = (float*)d_ws;
    float* hwbuf = dinv + Na;               // nd floats reserved; used as nd halves
    __half* hwh  = (__half*)hwbuf;

    // CSR arrays: primary = in d_ws (after hwbuf); fallback = in outA region.
    const size_t need_ints = (size_t)Na + (size_t)nd + 4ull * Na + NBa + 256 + 2ull * Ea;
    const bool ws_csr = ws_size >= need_ints * sizeof(int);

    int* base = ws_csr ? (int*)(hwbuf + nd) : (int*)outA;
    int* cnt     = base;                    // Na
    int* incl    = cnt + Na;                // Na
    int* bsum    = incl + Na;               // NBa
    int* offsets = bsum + NBa;              // Na + 256
    int* cursor  = offsets + Na + 256;      // Na
    int2* er     = (int2*)(cursor + Na);    // E records

    // ---- build CSR (sorted-by-dst packed edge records) ----
    hipMemsetAsync(cnt, 0, (size_t)n * sizeof(int), stream);
    cnt_kernel<<<(E + 255) / 256, 256, 0, stream>>>(dst, cnt, E);
    scan1_kernel<<<NB, 256, 0, stream>>>(cnt, incl, bsum, n);
    scan2_kernel<<<1, 256, 0, stream>>>(bsum, NB);
    scan3_kernel<<<NB, 256, 0, stream>>>(cnt, incl, bsum, offsets, cursor, dinv, n, E);
    fill_kernel<<<(E + 255) / 256, 256, 0, stream>>>(src, dst, cursor, dinv, er, E);

    dim3 ggrid((n + 127) / 128);
    const int pull_grid = (n + 3) / 4;

    if (ws_csr) {
        // layer 1: hw1 = fp16(x@W1) -> hwh; h = relu(agg) -> outB (f32)
        gemm_kernel<1><<<ggrid, 256, 0, stream>>>(x, W1, hwh, n);
        pull_kernel<<<pull_grid, 256, 0, stream>>>(hwh, offsets, er, dinv, b1,
                                                   outB, nullptr, n, 1);
        // layer 2: hw2 = fp16(h@W2) -> hwh; out = agg -> both halves (f32)
        gemm_kernel<1><<<ggrid, 256, 0, stream>>>(outB, W2, hwh, n);
        pull_kernel<<<pull_grid, 256, 0, stream>>>(hwh, offsets, er, dinv, b2,
                                                   outA, outB, n, 0);
    } else {
        // fallback (CSR scratch occupies outA until the end)
        __half* hwh2 = (__half*)outB;
        gemm_kernel<1><<<ggrid, 256, 0, stream>>>(x, W1, hwh2, n);
        pull_kernel<<<pull_grid, 256, 0, stream>>>(hwh2, offsets, er, dinv, b1,
                                                   hwbuf, nullptr, n, 1);
        gemm_kernel<1><<<ggrid, 256, 0, stream>>>(hwbuf, W2, hwh2, n);
        pull_kernel<<<pull_grid, 256, 0, stream>>>(hwh2, offsets, er, dinv, b2,
                                                   hwbuf, nullptr, n, 0);
        const int n4 = (int)(nd / 4);
        dup_kernel<<<(n4 + 255) / 256, 256, 0, stream>>>((const float4*)hwbuf,
                                                         (float4*)outA, (float4*)outB, n4);
    }
}

// Round 3
// 552.218 us; speedup vs baseline: 1.3298x; 1.1396x over previous
//
#include <hip/hip_runtime.h>
#include <hip/hip_fp16.h>

#define DMODEL 128

typedef _Float16 h8 __attribute__((ext_vector_type(8)));
typedef float fx4 __attribute__((ext_vector_type(4)));

// ================= CSR build =================
__global__ void cnt_kernel(const int* __restrict__ dst, int* __restrict__ cnt, int E) {
    int e = blockIdx.x * blockDim.x + threadIdx.x;
    if (e < E) atomicAdd(&cnt[dst[e]], 1);
}

__global__ void scan1_kernel(const int* __restrict__ cnt, int* __restrict__ incl,
                             int* __restrict__ bsum, int n) {
    __shared__ int s[256];
    int t = threadIdx.x;
    int i = blockIdx.x * 256 + t;
    int v = (i < n) ? cnt[i] : 0;
    s[t] = v;
    __syncthreads();
    for (int off = 1; off < 256; off <<= 1) {
        int add = (t >= off) ? s[t - off] : 0;
        __syncthreads();
        s[t] += add;
        __syncthreads();
    }
    if (i < n) incl[i] = s[t];
    if (t == 255) bsum[blockIdx.x] = s[255];
}

__global__ void scan2_kernel(int* __restrict__ bsum, int nb) {
    __shared__ int s[256];
    __shared__ int carry;
    int t = threadIdx.x;
    if (t == 0) carry = 0;
    __syncthreads();
    for (int base = 0; base < nb; base += 256) {
        int idx = base + t;
        int v = (idx < nb) ? bsum[idx] : 0;
        s[t] = v;
        __syncthreads();
        for (int off = 1; off < 256; off <<= 1) {
            int add = (t >= off) ? s[t - off] : 0;
            __syncthreads();
            s[t] += add;
            __syncthreads();
        }
        int excl = carry + s[t] - v;
        if (idx < nb) bsum[idx] = excl;
        __syncthreads();
        if (t == 255) carry += s[255];
    }
}

__global__ void scan3_kernel(const int* __restrict__ cnt, const int* __restrict__ incl,
                             const int* __restrict__ bsum, int* __restrict__ offsets,
                             int* __restrict__ cursor, float* __restrict__ dinv,
                             int n, int E) {
    int i = blockIdx.x * 256 + threadIdx.x;
    if (i < n) {
        int v = cnt[i];
        int excl = incl[i] - v + bsum[blockIdx.x];
        offsets[i] = excl;
        cursor[i] = excl;
        dinv[i] = rsqrtf((float)v + 1.0f);
    }
    if (i == 0) offsets[n] = E;
}

__global__ void fill_kernel(const int* __restrict__ src, const int* __restrict__ dst,
                            int* __restrict__ cursor, const float* __restrict__ dinv,
                            int2* __restrict__ er, int E) {
    int e = blockIdx.x * blockDim.x + threadIdx.x;
    if (e < E) {
        int s = src[e];
        int d = dst[e];
        int p = atomicAdd(&cursor[d], 1);
        er[p] = make_int2(s, __float_as_int(dinv[s] * dinv[d]));
    }
}

// W[k][c] f32 -> Wt[c][k] fp16 (transposed, MFMA B-operand layout). 32 KB, ~2 µs.
__global__ void wconv_kernel(const float* __restrict__ W, __half* __restrict__ Wt) {
    int i = blockIdx.x * 256 + threadIdx.x;   // 16384 elements
    int k = i >> 7, c = i & 127;
    Wt[c * 128 + k] = (__half)W[i];
}

// ================= MFMA GEMM: C[n,128](fp16) = A[n,128] * W[128,128] =================
// 128-row block, full N=128, K=128 single shot. 4 waves; wave owns 32 rows.
// mfma_f32_16x16x32_f16: A row=lane&15, k=(lane>>4)*8+j; B col=lane&15, same k;
// D col=lane&15, row=(lane>>4)*4+reg.  LDS tiles XOR-swizzled (16B granule ^ (row&7))
// to kill the 256B-row-stride bank conflict (T2). C bounced via LDS for 16B stores.
template <int A_F16>
__global__ __launch_bounds__(256) void gemm_mfma(const void* __restrict__ Ain,
                                                 const __half* __restrict__ Wt,
                                                 __half* __restrict__ C, int n) {
    __shared__ _Float16 sA[128][128];   // 32 KB
    __shared__ _Float16 sB[128][128];   // 32 KB  ([c][k])
    const int tid  = threadIdx.x;
    const int row0 = blockIdx.x * 128;

    // stage B (Wt already [c][k] fp16): swizzled store
#pragma unroll
    for (int p = 0; p < 8; ++p) {
        int f = p * 256 + tid;
        int c = f >> 4, seg = f & 15;
        uint4 v = *(const uint4*)&Wt[(size_t)c * 128 + seg * 8];
        *(uint4*)((char*)&sB[c][0] + (((seg ^ (c & 7)) << 4))) = v;
    }
    if (A_F16) {
        const __half* Ah = (const __half*)Ain;
#pragma unroll
        for (int p = 0; p < 8; ++p) {
            int f = p * 256 + tid;
            int r = f >> 4, seg = f & 15;
            int row = row0 + r;
            uint4 v = make_uint4(0, 0, 0, 0);
            if (row < n) v = *(const uint4*)&Ah[(size_t)row * 128 + seg * 8];
            *(uint4*)((char*)&sA[r][0] + (((seg ^ (r & 7)) << 4))) = v;
        }
    } else {
        const float* Af = (const float*)Ain;
#pragma unroll
        for (int p = 0; p < 16; ++p) {
            int f = p * 256 + tid;
            int r = f >> 5, c4 = f & 31;
            int row = row0 + r;
            float4 v = make_float4(0.f, 0.f, 0.f, 0.f);
            if (row < n) v = *(const float4*)&Af[(size_t)row * 128 + c4 * 4];
            union { _Float16 h[4]; uint2 u; } cv;
            cv.h[0] = (_Float16)v.x; cv.h[1] = (_Float16)v.y;
            cv.h[2] = (_Float16)v.z; cv.h[3] = (_Float16)v.w;
            int gsw = (c4 >> 1) ^ (r & 7);
            *(uint2*)((char*)&sA[r][0] + (gsw << 4) + ((c4 & 1) << 3)) = cv.u;
        }
    }
    __syncthreads();

    const int lane = tid & 63;
    const int w    = tid >> 6;
    const int c15  = lane & 15;
    const int g    = lane >> 4;

    fx4 acc[2][8];
#pragma unroll
    for (int i = 0; i < 2; ++i)
#pragma unroll
        for (int j = 0; j < 8; ++j) acc[i][j] = (fx4){0.f, 0.f, 0.f, 0.f};

    const int rA0 = w * 32 + c15;
    const int rA1 = rA0 + 16;
#pragma unroll
    for (int ks = 0; ks < 4; ++ks) {
        int kg = ks * 4 + g;            // 16B-granule index along k
        h8 a0 = *(h8*)((char*)&sA[rA0][0] + ((kg ^ (rA0 & 7)) << 4));
        h8 a1 = *(h8*)((char*)&sA[rA1][0] + ((kg ^ (rA1 & 7)) << 4));
#pragma unroll
        for (int tn = 0; tn < 8; ++tn) {
            int cb = tn * 16 + c15;
            h8 b = *(h8*)((char*)&sB[cb][0] + ((kg ^ (cb & 7)) << 4));
            acc[0][tn] = __builtin_amdgcn_mfma_f32_16x16x32_f16(a0, b, acc[0][tn], 0, 0, 0);
            acc[1][tn] = __builtin_amdgcn_mfma_f32_16x16x32_f16(a1, b, acc[1][tn], 0, 0, 0);
        }
    }

    __syncthreads();                    // all waves done reading sA
    _Float16* sC = &sA[0][0];           // reuse as C bounce, same swizzle family
#pragma unroll
    for (int tm = 0; tm < 2; ++tm) {
#pragma unroll
        for (int tn = 0; tn < 8; ++tn) {
#pragma unroll
            for (int j = 0; j < 4; ++j) {
                int r = w * 32 + tm * 16 + g * 4 + j;
                int c = tn * 16 + c15;
                *(_Float16*)((char*)(sC + (size_t)r * 128) +
                             (((c >> 3) ^ (r & 7)) << 4) + ((c & 7) << 1)) =
                    (_Float16)acc[tm][tn][j];
            }
        }
    }
    __syncthreads();
#pragma unroll
    for (int p = 0; p < 8; ++p) {
        int f = p * 256 + tid;
        int r = f >> 4, seg = f & 15;
        int row = row0 + r;
        if (row < n) {
            uint4 v = *(uint4*)((char*)(sC + (size_t)r * 128) + ((seg ^ (r & 7)) << 4));
            *(uint4*)&C[(size_t)row * 128 + seg * 8] = v;
        }
    }
}

// ================= pull aggregation (fused self-loop + bias + relu) =================
// one wave per node; lane owns 2 channels (half2 = 4B/lane); 4-way unrolled gathers.
// OUT_HALF: write result as fp16 (feeds next gemm's A operand), else f32 (+optional dup).
template <int OUT_HALF>
__global__ __launch_bounds__(256) void pull_kernel(const __half* __restrict__ hw,
                                                   const int* __restrict__ offsets,
                                                   const int2* __restrict__ er,
                                                   const float* __restrict__ dinv,
                                                   const float* __restrict__ bias,
                                                   void* __restrict__ out1,
                                                   void* __restrict__ out2,
                                                   int n, int relu) {
    int node = blockIdx.x * 4 + (threadIdx.x >> 6);
    int lane = threadIdx.x & 63;
    if (node >= n) return;
    const __half2* hwv = (const __half2*)hw;
    float di = dinv[node];
    float s2 = di * di;
    float2 selfv = __half22float2(hwv[(size_t)node * 64 + lane]);
    float2 a0, a1, a2, a3;
    a0.x = selfv.x * s2 + bias[lane * 2];
    a0.y = selfv.y * s2 + bias[lane * 2 + 1];
    a1 = make_float2(0.f, 0.f);
    a2 = make_float2(0.f, 0.f);
    a3 = make_float2(0.f, 0.f);
    int e0 = offsets[node];
    int e1 = offsets[node + 1];
    int e = e0;
    for (; e + 4 <= e1; e += 4) {
        int2 r0 = er[e];
        int2 r1 = er[e + 1];
        int2 r2 = er[e + 2];
        int2 r3 = er[e + 3];
        float2 v0 = __half22float2(hwv[(size_t)r0.x * 64 + lane]);
        float2 v1 = __half22float2(hwv[(size_t)r1.x * 64 + lane]);
        float2 v2 = __half22float2(hwv[(size_t)r2.x * 64 + lane]);
        float2 v3 = __half22float2(hwv[(size_t)r3.x * 64 + lane]);
        float w0 = __int_as_float(r0.y);
        float w1 = __int_as_float(r1.y);
        float w2 = __int_as_float(r2.y);
        float w3 = __int_as_float(r3.y);
        a0.x += v0.x * w0; a0.y += v0.y * w0;
        a1.x += v1.x * w1; a1.y += v1.y * w1;
        a2.x += v2.x * w2; a2.y += v2.y * w2;
        a3.x += v3.x * w3; a3.y += v3.y * w3;
    }
    for (; e < e1; ++e) {
        int2 r = er[e];
        float w = __int_as_float(r.y);
        float2 v = __half22float2(hwv[(size_t)r.x * 64 + lane]);
        a0.x += v.x * w;
        a0.y += v.y * w;
    }
    float2 acc;
    acc.x = (a0.x + a1.x) + (a2.x + a3.x);
    acc.y = (a0.y + a1.y) + (a2.y + a3.y);
    if (relu) {
        acc.x = fmaxf(acc.x, 0.f);
        acc.y = fmaxf(acc.y, 0.f);
    }
    if (OUT_HALF) {
        ((__half2*)out1)[(size_t)node * 64 + lane] = __floats2half2_rn(acc.x, acc.y);
    } else {
        ((float2*)out1)[(size_t)node * 64 + lane] = acc;
        if (out2) ((float2*)out2)[(size_t)node * 64 + lane] = acc;
    }
}

// duplicate result into both output halves (fallback path only)
__global__ void dup_kernel(const float4* __restrict__ s, float4* __restrict__ a,
                           float4* __restrict__ b, int n4) {
    int i = blockIdx.x * blockDim.x + threadIdx.x;
    if (i < n4) {
        float4 v = s[i];
        a[i] = v;
        b[i] = v;
    }
}

extern "C" void kernel_launch(void* const* d_in, const int* in_sizes, int n_in,
                              void* d_out, int out_size, void* d_ws, size_t ws_size,
                              hipStream_t stream) {
    const float* x  = (const float*)d_in[0];
    const int*   ei = (const int*)d_in[1];
    const float* W1 = (const float*)d_in[2];
    const float* b1 = (const float*)d_in[3];
    const float* W2 = (const float*)d_in[4];
    const float* b2 = (const float*)d_in[5];
    float* out = (float*)d_out;

    const int n = in_sizes[0] / DMODEL;     // 169343
    const int E = in_sizes[1] / 2;          // 1166243
    const int* src = ei;
    const int* dst = ei + E;

    const long long nd = (long long)n * DMODEL;
    const int NB = (n + 255) / 256;
    const int Na = NB * 256;
    const int NBa = ((NB + 255) / 256) * 256;
    const int Ea = ((E + 255) / 256) * 256;

    float* outA = out;
    float* outB = out + nd;

    // ---- d_ws: dinv + hw/h fp16 buffers (share the nd-float region) ----
    float* dinv  = (float*)d_ws;
    float* hwbuf = dinv + Na;               // nd floats = 2*nd halves
    __half* hwh  = (__half*)hwbuf;          // nd halves: hw (gemm out / pull in)
    __half* hh   = hwh + nd;                // nd halves: h  (pull1 out / gemm2 in)

    const size_t need_ints = (size_t)Na + (size_t)nd + 4ull * Na + NBa + 256 +
                             2ull * Ea + 16384;
    const bool ws_csr = ws_size >= need_ints * sizeof(int);

    int* base = ws_csr ? (int*)(hwbuf + nd) : (int*)outA;
    int* cnt     = base;                    // Na
    int* incl    = cnt + Na;                // Na
    int* bsum    = incl + Na;               // NBa
    int* offsets = bsum + NBa;              // Na + 256
    int* cursor  = offsets + Na + 256;      // Na
    int2* er     = (int2*)(cursor + Na);    // Ea records
    __half* Wt1  = (__half*)(er + Ea);      // 16384 halves
    __half* Wt2  = Wt1 + 16384;             // 16384 halves

    // ---- build CSR + transposed fp16 weights ----
    hipMemsetAsync(cnt, 0, (size_t)n * sizeof(int), stream);
    cnt_kernel<<<(E + 255) / 256, 256, 0, stream>>>(dst, cnt, E);
    scan1_kernel<<<NB, 256, 0, stream>>>(cnt, incl, bsum, n);
    scan2_kernel<<<1, 256, 0, stream>>>(bsum, NB);
    scan3_kernel<<<NB, 256, 0, stream>>>(cnt, incl, bsum, offsets, cursor, dinv, n, E);
    fill_kernel<<<(E + 255) / 256, 256, 0, stream>>>(src, dst, cursor, dinv, er, E);
    wconv_kernel<<<64, 256, 0, stream>>>(W1, Wt1);
    wconv_kernel<<<64, 256, 0, stream>>>(W2, Wt2);

    dim3 ggrid((n + 127) / 128);
    const int pull_grid = (n + 3) / 4;

    if (ws_csr) {
        // layer 1: hw1 = fp16(x@W1); h = fp16(relu(agg)) -> hh
        gemm_mfma<0><<<ggrid, 256, 0, stream>>>(x, Wt1, hwh, n);
        pull_kernel<1><<<pull_grid, 256, 0, stream>>>(hwh, offsets, er, dinv, b1,
                                                      hh, nullptr, n, 1);
        // layer 2: hw2 = fp16(h@W2); out = agg -> both f32 halves
        gemm_mfma<1><<<ggrid, 256, 0, stream>>>(hh, Wt2, hwh, n);
        pull_kernel<0><<<pull_grid, 256, 0, stream>>>(hwh, offsets, er, dinv, b2,
                                                      outA, outB, n, 0);
    } else {
        // fallback: CSR + Wt in outA region; hw/h fp16 in outB region; result via ws
        __half* hwh2 = (__half*)outB;       // nd halves
        __half* hh2  = hwh2 + nd;           // nd halves
        gemm_mfma<0><<<ggrid, 256, 0, stream>>>(x, Wt1, hwh2, n);
        pull_kernel<1><<<pull_grid, 256, 0, stream>>>(hwh2, offsets, er, dinv, b1,
                                                      hh2, nullptr, n, 1);
        gemm_mfma<1><<<ggrid, 256, 0, stream>>>(hh2, Wt2, hwh2, n);
        pull_kernel<0><<<pull_grid, 256, 0, stream>>>(hwh2, offsets, er, dinv, b2,
                                                      hwbuf, nullptr, n, 0);
        const int n4 = (int)(nd / 4);
        dup_kernel<<<(n4 + 255) / 256, 256, 0, stream>>>((const float4*)hwbuf,
                                                         (float4*)outA, (float4*)outB, n4);
    }
}